// Round 1
// baseline (8359.755 us; speedup 1.0000x reference)
//
#include <hip/hip_runtime.h>
#include <hip/hip_bf16.h>

#define LRELU(a) ((a) >= 0.0f ? (a) : 0.2f * (a))
#define NEG_INF_KEY 0x007FFFFFu

__device__ __forceinline__ unsigned enc_f(float f) {
    unsigned u = __float_as_uint(f);
    return (u & 0x80000000u) ? ~u : (u | 0x80000000u);
}
__device__ __forceinline__ float dec_f(unsigned u) {
    return (u & 0x80000000u) ? __uint_as_float(u & 0x7FFFFFFFu) : __uint_as_float(~u);
}

// ---------------- GEMM: C[M,Nc] = A[M,K] @ B[K,Nc], fp32, 64x64x16 tiles ----------------
__global__ __launch_bounds__(256) void gemm_f32(const float* __restrict__ A,
                                                const float* __restrict__ B,
                                                float* __restrict__ C,
                                                int M, int Nc, int K) {
    __shared__ float As[16][68];  // [k][m], pad 68 -> aligned float4 reads + low conflict
    __shared__ float Bs[16][68];  // [k][n]
    int tid = threadIdx.x;
    int tx = tid & 15, ty = tid >> 4;
    int m0 = blockIdx.y * 64, n0 = blockIdx.x * 64;
    float acc[4][4] = {};
    for (int k0 = 0; k0 < K; k0 += 16) {
        #pragma unroll
        for (int j = 0; j < 4; ++j) {
            int m = (tid >> 4) + 16 * j;
            int k = tid & 15;
            int row = m0 + m;
            As[k][m] = (row < M) ? A[(size_t)row * K + k0 + k] : 0.0f;
        }
        #pragma unroll
        for (int j = 0; j < 4; ++j) {
            int n = tid & 63;
            int k = (tid >> 6) + 4 * j;
            Bs[k][n] = B[(size_t)(k0 + k) * Nc + n0 + n];
        }
        __syncthreads();
        #pragma unroll
        for (int k = 0; k < 16; ++k) {
            float4 a4 = *(const float4*)&As[k][ty * 4];
            float4 b4 = *(const float4*)&Bs[k][tx * 4];
            float av[4] = {a4.x, a4.y, a4.z, a4.w};
            float bv[4] = {b4.x, b4.y, b4.z, b4.w};
            #pragma unroll
            for (int r = 0; r < 4; ++r)
                #pragma unroll
                for (int c = 0; c < 4; ++c)
                    acc[r][c] += av[r] * bv[c];
        }
        __syncthreads();
    }
    #pragma unroll
    for (int r = 0; r < 4; ++r) {
        int row = m0 + ty * 4 + r;
        if (row < M) {
            float4 o = make_float4(acc[r][0], acc[r][1], acc[r][2], acc[r][3]);
            *(float4*)&C[(size_t)row * Nc + n0 + tx * 4] = o;
        }
    }
}

// ---------------- Layer-1 attention scores: a_src[n,h] = sum_c h1[n,h,c]*att[h,c] ----------------
__global__ __launch_bounds__(256) void att_scores1(const float* __restrict__ h1,
                                                   const float* __restrict__ att_src,
                                                   const float* __restrict__ att_dst,
                                                   float* __restrict__ a_src,
                                                   float* __restrict__ a_dst, int N) {
    int n = blockIdx.x;
    int t = threadIdx.x;  // column 0..255; head = t>>5
    float v = h1[(size_t)n * 256 + t];
    float ps = v * att_src[t];
    float pd = v * att_dst[t];
    #pragma unroll
    for (int m = 16; m >= 1; m >>= 1) {
        ps += __shfl_xor(ps, m);
        pd += __shfl_xor(pd, m);
    }
    if ((t & 31) == 0) {
        a_src[(size_t)n * 8 + (t >> 5)] = ps;
        a_dst[(size_t)n * 8 + (t >> 5)] = pd;
    }
}

__global__ void init_max_denom(unsigned* __restrict__ keys, float* __restrict__ denom, int n) {
    int i = blockIdx.x * blockDim.x + threadIdx.x;
    if (i < n) { keys[i] = NEG_INF_KEY; denom[i] = 0.0f; }
}

__global__ __launch_bounds__(256) void edge_max1(const int* __restrict__ src, const int* __restrict__ dst,
                                                 const float* __restrict__ a_src, const float* __restrict__ a_dst,
                                                 unsigned* __restrict__ keys, int E) {
    int e = blockIdx.x * 256 + threadIdx.x;
    if (e >= E) return;
    int s = src[e], d = dst[e];
    const float4* ps = (const float4*)(a_src + (size_t)s * 8);
    const float4* pd = (const float4*)(a_dst + (size_t)d * 8);
    float4 s0 = ps[0], s1 = ps[1], d0 = pd[0], d1 = pd[1];
    float al[8] = {s0.x + d0.x, s0.y + d0.y, s0.z + d0.z, s0.w + d0.w,
                   s1.x + d1.x, s1.y + d1.y, s1.z + d1.z, s1.w + d1.w};
    #pragma unroll
    for (int h = 0; h < 8; ++h) {
        float a = LRELU(al[h]);
        atomicMax(&keys[(size_t)d * 8 + h], enc_f(a));
    }
}

__global__ void fix_amax(const unsigned* __restrict__ keys, float* __restrict__ amax, int n) {
    int i = blockIdx.x * blockDim.x + threadIdx.x;
    if (i < n) {
        unsigned u = keys[i];
        amax[i] = (u == NEG_INF_KEY) ? 0.0f : dec_f(u);
    }
}

__global__ __launch_bounds__(256) void edge_sum1(const int* __restrict__ src, const int* __restrict__ dst,
                                                 const float* __restrict__ a_src, const float* __restrict__ a_dst,
                                                 const float* __restrict__ amax, float* __restrict__ denom, int E) {
    int e = blockIdx.x * 256 + threadIdx.x;
    if (e >= E) return;
    int s = src[e], d = dst[e];
    const float4* ps = (const float4*)(a_src + (size_t)s * 8);
    const float4* pd = (const float4*)(a_dst + (size_t)d * 8);
    const float4* pm = (const float4*)(amax + (size_t)d * 8);
    float4 s0 = ps[0], s1 = ps[1], d0 = pd[0], d1 = pd[1], m0 = pm[0], m1 = pm[1];
    float al[8] = {s0.x + d0.x, s0.y + d0.y, s0.z + d0.z, s0.w + d0.w,
                   s1.x + d1.x, s1.y + d1.y, s1.z + d1.z, s1.w + d1.w};
    float mx[8] = {m0.x, m0.y, m0.z, m0.w, m1.x, m1.y, m1.z, m1.w};
    #pragma unroll
    for (int h = 0; h < 8; ++h) {
        float a = LRELU(al[h]);
        atomicAdd(&denom[(size_t)d * 8 + h], expf(a - mx[h]));
    }
}

// One wave per edge: gather h1[src] row (256 f32), scale by attn[head], scatter-add into out1[dst]
__global__ __launch_bounds__(256) void edge_agg1(const int* __restrict__ src, const int* __restrict__ dst,
                                                 const float* __restrict__ a_src, const float* __restrict__ a_dst,
                                                 const float* __restrict__ amax, const float* __restrict__ denom,
                                                 const float* __restrict__ h1, float* __restrict__ out1, int E) {
    int gid = blockIdx.x * 256 + threadIdx.x;
    int e = gid >> 6;
    if (e >= E) return;
    int lane = threadIdx.x & 63;
    int s = src[e], d = dst[e];
    int h = lane & 7;  // lanes 0..7 hold heads 0..7 (redundantly computed by all lanes)
    float a = a_src[(size_t)s * 8 + h] + a_dst[(size_t)d * 8 + h];
    a = LRELU(a);
    float ex = expf(a - amax[(size_t)d * 8 + h]);
    float at = ex / (denom[(size_t)d * 8 + h] + 1e-16f);
    float myat = __shfl(at, lane >> 3);  // lane covers cols lane*4..lane*4+3 -> head lane>>3
    float4 hv = *(const float4*)(h1 + (size_t)s * 256 + lane * 4);
    float* ob = out1 + (size_t)d * 256 + lane * 4;
    atomicAdd(ob + 0, hv.x * myat);
    atomicAdd(ob + 1, hv.y * myat);
    atomicAdd(ob + 2, hv.z * myat);
    atomicAdd(ob + 3, hv.w * myat);
}

__global__ void elu_inplace(float* __restrict__ p, int n) {
    int i = blockIdx.x * blockDim.x + threadIdx.x;
    if (i < n) {
        float v = p[i];
        p[i] = v > 0.0f ? v : expm1f(v);
    }
}

// ---------------- Layer-2 (H=1, C=64) ----------------
__global__ __launch_bounds__(256) void att_scores2(const float* __restrict__ h2,
                                                   const float* __restrict__ att_src,
                                                   const float* __restrict__ att_dst,
                                                   float* __restrict__ a_src, float* __restrict__ a_dst, int N) {
    int n = blockIdx.x * 4 + (threadIdx.x >> 6);
    int lane = threadIdx.x & 63;
    if (n >= N) return;
    float v = h2[(size_t)n * 64 + lane];
    float ps = v * att_src[lane];
    float pd = v * att_dst[lane];
    #pragma unroll
    for (int m = 32; m >= 1; m >>= 1) {
        ps += __shfl_xor(ps, m);
        pd += __shfl_xor(pd, m);
    }
    if (lane == 0) { a_src[n] = ps; a_dst[n] = pd; }
}

__global__ __launch_bounds__(256) void edge_max2(const int* __restrict__ src, const int* __restrict__ dst,
                                                 const float* __restrict__ a_src, const float* __restrict__ a_dst,
                                                 unsigned* __restrict__ keys, int E) {
    int e = blockIdx.x * 256 + threadIdx.x;
    if (e >= E) return;
    int s = src[e], d = dst[e];
    float a = LRELU(a_src[s] + a_dst[d]);
    atomicMax(&keys[d], enc_f(a));
}

__global__ __launch_bounds__(256) void edge_sum2(const int* __restrict__ src, const int* __restrict__ dst,
                                                 const float* __restrict__ a_src, const float* __restrict__ a_dst,
                                                 const float* __restrict__ amax, float* __restrict__ denom, int E) {
    int e = blockIdx.x * 256 + threadIdx.x;
    if (e >= E) return;
    int s = src[e], d = dst[e];
    float a = LRELU(a_src[s] + a_dst[d]);
    atomicAdd(&denom[d], expf(a - amax[d]));
}

// 16 lanes per edge: gather h2[src] (64 f32), scatter-add into out[dst]
__global__ __launch_bounds__(256) void edge_agg2(const int* __restrict__ src, const int* __restrict__ dst,
                                                 const float* __restrict__ a_src, const float* __restrict__ a_dst,
                                                 const float* __restrict__ amax, const float* __restrict__ denom,
                                                 const float* __restrict__ h2, float* __restrict__ out, int E) {
    int gid = blockIdx.x * 256 + threadIdx.x;
    int e = gid >> 4;
    if (e >= E) return;
    int li = gid & 15;
    int s = src[e], d = dst[e];
    float a = LRELU(a_src[s] + a_dst[d]);
    float at = expf(a - amax[d]) / (denom[d] + 1e-16f);
    float4 hv = *(const float4*)(h2 + (size_t)s * 64 + li * 4);
    float* ob = out + (size_t)d * 64 + li * 4;
    atomicAdd(ob + 0, hv.x * at);
    atomicAdd(ob + 1, hv.y * at);
    atomicAdd(ob + 2, hv.z * at);
    atomicAdd(ob + 3, hv.w * at);
}

extern "C" void kernel_launch(void* const* d_in, const int* in_sizes, int n_in,
                              void* d_out, int out_size, void* d_ws, size_t ws_size,
                              hipStream_t stream) {
    const float* x        = (const float*)d_in[0];
    const float* W1       = (const float*)d_in[1];
    const float* att_src1 = (const float*)d_in[2];
    const float* att_dst1 = (const float*)d_in[3];
    const float* W2       = (const float*)d_in[4];
    const float* att_src2 = (const float*)d_in[5];
    const float* att_dst2 = (const float*)d_in[6];
    const int*   ei       = (const int*)d_in[7];

    int N = in_sizes[0] / 256;
    int E = in_sizes[7] / 2;
    const int* src = ei;
    const int* dst = ei + E;

    float* ws = (float*)d_ws;
    float* h1      = ws;                               // [N,256]
    float* out1    = h1 + (size_t)N * 256;             // [N,256]
    float* a_src1v = out1 + (size_t)N * 256;           // [N,8]
    float* a_dst1v = a_src1v + (size_t)N * 8;          // [N,8]
    unsigned* key1 = (unsigned*)(a_dst1v + (size_t)N * 8);  // [N,8]
    float* amax1   = (float*)key1 + (size_t)N * 8;     // [N,8]
    float* denom1  = amax1 + (size_t)N * 8;            // [N,8]
    float* a_src2v = denom1 + (size_t)N * 8;           // [N]
    float* a_dst2v = a_src2v + N;                      // [N]
    unsigned* key2 = (unsigned*)(a_dst2v + N);         // [N]
    float* amax2   = (float*)key2 + N;                 // [N]
    float* denom2  = amax2 + N;                        // [N]
    float* h2      = h1;                               // alias: h1 dead after layer-1 agg

    float* outf = (float*)d_out;

    hipMemsetAsync(out1, 0, (size_t)N * 256 * sizeof(float), stream);
    hipMemsetAsync(outf, 0, (size_t)out_size * sizeof(float), stream);

    // ---- layer 1 ----
    gemm_f32<<<dim3(256 / 64, (N + 63) / 64), 256, 0, stream>>>(x, W1, h1, N, 256, 256);
    att_scores1<<<N, 256, 0, stream>>>(h1, att_src1, att_dst1, a_src1v, a_dst1v, N);
    init_max_denom<<<(N * 8 + 255) / 256, 256, 0, stream>>>(key1, denom1, N * 8);
    edge_max1<<<(E + 255) / 256, 256, 0, stream>>>(src, dst, a_src1v, a_dst1v, key1, E);
    fix_amax<<<(N * 8 + 255) / 256, 256, 0, stream>>>(key1, amax1, N * 8);
    edge_sum1<<<(E + 255) / 256, 256, 0, stream>>>(src, dst, a_src1v, a_dst1v, amax1, denom1, E);
    edge_agg1<<<(int)(((size_t)E * 64 + 255) / 256), 256, 0, stream>>>(src, dst, a_src1v, a_dst1v,
                                                                       amax1, denom1, h1, out1, E);
    elu_inplace<<<(N * 256 + 255) / 256, 256, 0, stream>>>(out1, N * 256);

    // ---- layer 2 ----
    gemm_f32<<<dim3(1, (N + 63) / 64), 256, 0, stream>>>(out1, W2, h2, N, 64, 256);
    att_scores2<<<(N + 3) / 4, 256, 0, stream>>>(h2, att_src2, att_dst2, a_src2v, a_dst2v, N);
    init_max_denom<<<(N + 255) / 256, 256, 0, stream>>>(key2, denom2, N);
    edge_max2<<<(E + 255) / 256, 256, 0, stream>>>(src, dst, a_src2v, a_dst2v, key2, E);
    fix_amax<<<(N + 255) / 256, 256, 0, stream>>>(key2, amax2, N);
    edge_sum2<<<(E + 255) / 256, 256, 0, stream>>>(src, dst, a_src2v, a_dst2v, amax2, denom2, E);
    edge_agg2<<<(int)(((size_t)E * 16 + 255) / 256), 256, 0, stream>>>(src, dst, a_src2v, a_dst2v,
                                                                       amax2, denom2, h2, outf, E);
}

// Round 2
// 1105.452 us; speedup vs baseline: 7.5623x; 7.5623x over previous
//
#include <hip/hip_runtime.h>
#include <hip/hip_bf16.h>

#define LRELU(a) ((a) >= 0.0f ? (a) : 0.2f * (a))

// ---------------- GEMM: C[M,Nc] = A[M,K] @ B[K,Nc], fp32, 64x64x16 tiles ----------------
__global__ __launch_bounds__(256) void gemm_f32(const float* __restrict__ A,
                                                const float* __restrict__ B,
                                                float* __restrict__ C,
                                                int M, int Nc, int K) {
    __shared__ float As[16][68];
    __shared__ float Bs[16][68];
    int tid = threadIdx.x;
    int tx = tid & 15, ty = tid >> 4;
    int m0 = blockIdx.y * 64, n0 = blockIdx.x * 64;
    float acc[4][4] = {};
    for (int k0 = 0; k0 < K; k0 += 16) {
        #pragma unroll
        for (int j = 0; j < 4; ++j) {
            int m = (tid >> 4) + 16 * j;
            int k = tid & 15;
            int row = m0 + m;
            As[k][m] = (row < M) ? A[(size_t)row * K + k0 + k] : 0.0f;
        }
        #pragma unroll
        for (int j = 0; j < 4; ++j) {
            int n = tid & 63;
            int k = (tid >> 6) + 4 * j;
            Bs[k][n] = B[(size_t)(k0 + k) * Nc + n0 + n];
        }
        __syncthreads();
        #pragma unroll
        for (int k = 0; k < 16; ++k) {
            float4 a4 = *(const float4*)&As[k][ty * 4];
            float4 b4 = *(const float4*)&Bs[k][tx * 4];
            float av[4] = {a4.x, a4.y, a4.z, a4.w};
            float bv[4] = {b4.x, b4.y, b4.z, b4.w};
            #pragma unroll
            for (int r = 0; r < 4; ++r)
                #pragma unroll
                for (int c = 0; c < 4; ++c)
                    acc[r][c] += av[r] * bv[c];
        }
        __syncthreads();
    }
    #pragma unroll
    for (int r = 0; r < 4; ++r) {
        int row = m0 + ty * 4 + r;
        if (row < M) {
            float4 o = make_float4(acc[r][0], acc[r][1], acc[r][2], acc[r][3]);
            *(float4*)&C[(size_t)row * Nc + n0 + tx * 4] = o;
        }
    }
}

// ---------------- attention scores ----------------
__global__ __launch_bounds__(256) void att_scores1(const float* __restrict__ h1,
                                                   const float* __restrict__ att_src,
                                                   const float* __restrict__ att_dst,
                                                   float* __restrict__ a_src,
                                                   float* __restrict__ a_dst, int N) {
    int n = blockIdx.x;
    int t = threadIdx.x;  // column 0..255; head = t>>5
    float v = h1[(size_t)n * 256 + t];
    float ps = v * att_src[t];
    float pd = v * att_dst[t];
    #pragma unroll
    for (int m = 16; m >= 1; m >>= 1) {
        ps += __shfl_xor(ps, m);
        pd += __shfl_xor(pd, m);
    }
    if ((t & 31) == 0) {
        a_src[(size_t)n * 8 + (t >> 5)] = ps;
        a_dst[(size_t)n * 8 + (t >> 5)] = pd;
    }
}

__global__ __launch_bounds__(256) void att_scores2(const float* __restrict__ h2,
                                                   const float* __restrict__ att_src,
                                                   const float* __restrict__ att_dst,
                                                   float* __restrict__ a_src, float* __restrict__ a_dst, int N) {
    int n = blockIdx.x * 4 + (threadIdx.x >> 6);
    int lane = threadIdx.x & 63;
    if (n >= N) return;
    float v = h2[(size_t)n * 64 + lane];
    float ps = v * att_src[lane];
    float pd = v * att_dst[lane];
    #pragma unroll
    for (int m = 32; m >= 1; m >>= 1) {
        ps += __shfl_xor(ps, m);
        pd += __shfl_xor(pd, m);
    }
    if (lane == 0) { a_src[n] = ps; a_dst[n] = pd; }
}

// ---------------- CSR build (by dst) ----------------
__global__ __launch_bounds__(256) void hist_dst(const int* __restrict__ dst, unsigned* __restrict__ cnt, int E) {
    int e = blockIdx.x * 256 + threadIdx.x;
    if (e < E) atomicAdd(&cnt[dst[e]], 1u);
}

__global__ __launch_bounds__(256) void scan_partial(const unsigned* __restrict__ cnt,
                                                    int* __restrict__ rowptr,
                                                    unsigned* __restrict__ bsum, int n) {
    __shared__ unsigned s[256];
    int i = blockIdx.x * 256 + threadIdx.x;
    unsigned v = (i < n) ? cnt[i] : 0u;
    s[threadIdx.x] = v;
    __syncthreads();
    #pragma unroll
    for (int off = 1; off < 256; off <<= 1) {
        unsigned t = (threadIdx.x >= off) ? s[threadIdx.x - off] : 0u;
        __syncthreads();
        s[threadIdx.x] += t;
        __syncthreads();
    }
    if (i < n) rowptr[i + 1] = (int)s[threadIdx.x];
    if (threadIdx.x == 255) bsum[blockIdx.x] = s[255];
}

__global__ __launch_bounds__(512) void scan_bsum(unsigned* __restrict__ bsum, int nb) {
    __shared__ unsigned s[512];
    int t = threadIdx.x;
    s[t] = (t < nb) ? bsum[t] : 0u;
    __syncthreads();
    #pragma unroll
    for (int off = 1; off < 512; off <<= 1) {
        unsigned v = (t >= off) ? s[t - off] : 0u;
        __syncthreads();
        s[t] += v;
        __syncthreads();
    }
    unsigned ex = (t == 0) ? 0u : s[t - 1];
    if (t < nb) bsum[t] = ex;
}

__global__ __launch_bounds__(256) void scan_add(int* __restrict__ rowptr, const unsigned* __restrict__ boff, int n) {
    int i = blockIdx.x * 256 + threadIdx.x;
    if (i < n) rowptr[i + 1] += (int)boff[blockIdx.x];
    if (blockIdx.x == 0 && threadIdx.x == 0) rowptr[0] = 0;
}

__global__ __launch_bounds__(256) void scatter_edges(const int* __restrict__ dst, const int* __restrict__ rowptr,
                                                     unsigned* __restrict__ cnt, int* __restrict__ eidx, int E) {
    int e = blockIdx.x * 256 + threadIdx.x;
    if (e >= E) return;
    int d = dst[e];
    unsigned p = atomicAdd(&cnt[d], 1u);
    eidx[rowptr[d] + (int)p] = e;
}

// online-softmax pair merge, -inf safe
__device__ __forceinline__ void merge_ms(float& m, float& s, float mo, float so) {
    float mn = fmaxf(m, mo);
    float fa = (m == mn) ? 1.0f : expf(m - mn);
    float fb = (mo == mn) ? 1.0f : expf(mo - mn);
    s = s * fa + so * fb;
    m = mn;
}

// ---------------- Layer-1 aggregation: one wave per dst node ----------------
// pass 1: segment softmax stats in-register (lane l handles edge j+=8 for head l&7)
// pass 2: gather h1[src] rows (float4/lane, 1KB/edge coalesced), accumulate, one store
__global__ __launch_bounds__(256) void agg1(const int* __restrict__ src,
                                            const int* __restrict__ rowptr,
                                            const int* __restrict__ eidx,
                                            const float* __restrict__ a_src,
                                            const float* __restrict__ a_dst,
                                            const float* __restrict__ h1,
                                            float* __restrict__ out1, int N) {
    int wid = threadIdx.x >> 6;
    int lane = threadIdx.x & 63;
    int d = blockIdx.x * 4 + wid;
    if (d >= N) return;
    int beg = rowptr[d], end = rowptr[d + 1];

    int hp1 = lane & 7;
    float adst1 = a_dst[(size_t)d * 8 + hp1];
    float m = -INFINITY, ssum = 0.0f;
    for (int j = beg + (lane >> 3); j < end; j += 8) {
        int e = eidx[j];
        int s = src[e];
        float a = a_src[(size_t)s * 8 + hp1] + adst1;
        a = LRELU(a);
        if (a > m) { ssum *= expf(m - a); m = a; }
        ssum += expf(a - m);
    }
    #pragma unroll
    for (int mask = 8; mask < 64; mask <<= 1) {
        float mo = __shfl_xor(m, mask);
        float so = __shfl_xor(ssum, mask);
        merge_ms(m, ssum, mo, so);
    }
    int hp2 = lane >> 3;  // my float4 covers channels lane*4.. -> head lane>>3
    float mh = __shfl(m, hp2);
    float rden = 1.0f / (__shfl(ssum, hp2) + 1e-16f);
    float adst2 = a_dst[(size_t)d * 8 + hp2];

    float4 acc = make_float4(0.f, 0.f, 0.f, 0.f);
    for (int j = beg; j < end; ++j) {
        int e = eidx[j];
        int s = src[e];
        float a = LRELU(a_src[(size_t)s * 8 + hp2] + adst2);
        float at = expf(a - mh) * rden;
        float4 hv = *(const float4*)(h1 + (size_t)s * 256 + lane * 4);
        acc.x += hv.x * at;
        acc.y += hv.y * at;
        acc.z += hv.z * at;
        acc.w += hv.w * at;
    }
    *(float4*)(out1 + (size_t)d * 256 + lane * 4) = acc;
}

// ---------------- Layer-2 aggregation (H=1,C=64): one wave per dst node ----------------
__global__ __launch_bounds__(256) void agg2(const int* __restrict__ src,
                                            const int* __restrict__ rowptr,
                                            const int* __restrict__ eidx,
                                            const float* __restrict__ a_src,
                                            const float* __restrict__ a_dst,
                                            const float* __restrict__ h2,
                                            float* __restrict__ out, int N) {
    int wid = threadIdx.x >> 6;
    int lane = threadIdx.x & 63;
    int d = blockIdx.x * 4 + wid;
    if (d >= N) return;
    int beg = rowptr[d], end = rowptr[d + 1];
    float adst = a_dst[d];

    float m = -INFINITY, ssum = 0.0f;
    for (int j = beg + lane; j < end; j += 64) {
        int s = src[eidx[j]];
        float a = LRELU(a_src[s] + adst);
        if (a > m) { ssum *= expf(m - a); m = a; }
        ssum += expf(a - m);
    }
    #pragma unroll
    for (int mask = 1; mask < 64; mask <<= 1) {
        float mo = __shfl_xor(m, mask);
        float so = __shfl_xor(ssum, mask);
        merge_ms(m, ssum, mo, so);
    }
    float rden = 1.0f / (ssum + 1e-16f);

    float acc = 0.0f;
    for (int j = beg; j < end; ++j) {
        int s = src[eidx[j]];
        float a = LRELU(a_src[s] + adst);
        float at = expf(a - m) * rden;
        acc += h2[(size_t)s * 64 + lane] * at;
    }
    out[(size_t)d * 64 + lane] = acc;
}

__global__ __launch_bounds__(256) void elu_inplace4(float4* __restrict__ p, int n4) {
    int i = blockIdx.x * 256 + threadIdx.x;
    if (i < n4) {
        float4 v = p[i];
        v.x = v.x > 0.0f ? v.x : expm1f(v.x);
        v.y = v.y > 0.0f ? v.y : expm1f(v.y);
        v.z = v.z > 0.0f ? v.z : expm1f(v.z);
        v.w = v.w > 0.0f ? v.w : expm1f(v.w);
        p[i] = v;
    }
}

extern "C" void kernel_launch(void* const* d_in, const int* in_sizes, int n_in,
                              void* d_out, int out_size, void* d_ws, size_t ws_size,
                              hipStream_t stream) {
    const float* x        = (const float*)d_in[0];
    const float* W1       = (const float*)d_in[1];
    const float* att_src1 = (const float*)d_in[2];
    const float* att_dst1 = (const float*)d_in[3];
    const float* W2       = (const float*)d_in[4];
    const float* att_src2 = (const float*)d_in[5];
    const float* att_dst2 = (const float*)d_in[6];
    const int*   ei       = (const int*)d_in[7];

    int N = in_sizes[0] / 256;
    int E = in_sizes[7] / 2;
    const int* src = ei;
    const int* dst = ei + E;

    float* ws = (float*)d_ws;
    float* h1      = ws;                                   // [N,256]
    float* out1    = h1 + (size_t)N * 256;                 // [N,256]
    float* a_src1v = out1 + (size_t)N * 256;               // [N,8]
    float* a_dst1v = a_src1v + (size_t)N * 8;              // [N,8]
    float* a_src2v = a_dst1v + (size_t)N * 8;              // [N]
    float* a_dst2v = a_src2v + N;                          // [N]
    int*   rowptr  = (int*)(a_dst2v + N);                  // [N+1]
    unsigned* cnt  = (unsigned*)(rowptr + N + 1);          // [N]
    int*   eidx    = (int*)(cnt + N);                      // [E]
    unsigned* bsum = (unsigned*)(eidx + E);                // [512]
    float* h2      = h1;                                   // alias: h1 dead after agg1

    float* outf = (float*)d_out;

    int nb = (N + 255) / 256;  // 391 <= 512

    // ---- CSR build ----
    hipMemsetAsync(cnt, 0, (size_t)N * sizeof(unsigned), stream);
    hist_dst<<<(E + 255) / 256, 256, 0, stream>>>(dst, cnt, E);
    scan_partial<<<nb, 256, 0, stream>>>(cnt, rowptr, bsum, N);
    scan_bsum<<<1, 512, 0, stream>>>(bsum, nb);
    scan_add<<<nb, 256, 0, stream>>>(rowptr, bsum, N);
    hipMemsetAsync(cnt, 0, (size_t)N * sizeof(unsigned), stream);
    scatter_edges<<<(E + 255) / 256, 256, 0, stream>>>(dst, rowptr, cnt, eidx, E);

    // ---- layer 1 ----
    gemm_f32<<<dim3(256 / 64, (N + 63) / 64), 256, 0, stream>>>(x, W1, h1, N, 256, 256);
    att_scores1<<<N, 256, 0, stream>>>(h1, att_src1, att_dst1, a_src1v, a_dst1v, N);
    agg1<<<(N + 3) / 4, 256, 0, stream>>>(src, rowptr, eidx, a_src1v, a_dst1v, h1, out1, N);
    elu_inplace4<<<(N * 64 + 255) / 256, 256, 0, stream>>>((float4*)out1, N * 64);

    // ---- layer 2 ----
    gemm_f32<<<dim3(1, (N + 63) / 64), 256, 0, stream>>>(out1, W2, h2, N, 64, 256);
    att_scores2<<<(N + 3) / 4, 256, 0, stream>>>(h2, att_src2, att_dst2, a_src2v, a_dst2v, N);
    agg2<<<(N + 3) / 4, 256, 0, stream>>>(src, rowptr, eidx, a_src2v, a_dst2v, h2, outf, N);
}